// Round 13
// baseline (548.204 us; speedup 1.0000x reference)
//
#include <hip/hip_runtime.h>
#include <hip/hip_bf16.h>

typedef short bf16x8 __attribute__((ext_vector_type(8)));
typedef float f32x4  __attribute__((ext_vector_type(4)));

#define NB 64
#define NN 512
#define DD 128

// RNE float -> bf16 (finite inputs)
__device__ __forceinline__ unsigned short f2bf(float f) {
    unsigned int u = __float_as_uint(f);
    unsigned int r = (u + 0x7FFFu + ((u >> 16) & 1u)) >> 16;
    return (unsigned short)r;
}

// Kernel 1: per-row L2 normalize, write bf16 fn into workspace (XCD-pinned).
__global__ __launch_bounds__(256) void ASG_norm_kernel(
    const float* __restrict__ fea, unsigned int* __restrict__ fn)
{
    const int id   = blockIdx.x;        // 0..2047
    const int xcd  = id & 7;
    const int q    = id >> 3;           // 0..255
    const int b    = xcd + 8 * (q >> 5);
    const int t    = q & 31;            // 32 blocks/batch, 16 rows each
    const int wid  = threadIdx.x >> 6;
    const int lane = threadIdx.x & 63;
    const int row0 = b * NN + t * 16 + wid * 4;
    const float2* src = reinterpret_cast<const float2*>(fea);

    float2 v[4];
    float  s[4];
#pragma unroll
    for (int rr = 0; rr < 4; ++rr) {
        v[rr] = src[(size_t)(row0 + rr) * (DD / 2) + lane];
        s[rr] = v[rr].x * v[rr].x + v[rr].y * v[rr].y;
    }
#pragma unroll
    for (int o = 32; o; o >>= 1) {
#pragma unroll
        for (int rr = 0; rr < 4; ++rr) s[rr] += __shfl_xor(s[rr], o);
    }
#pragma unroll
    for (int rr = 0; rr < 4; ++rr) {
        const float scale = 1.0f / fmaxf(sqrtf(s[rr]), 1e-8f);
        const unsigned short a = f2bf(v[rr].x * scale);
        const unsigned short bb = f2bf(v[rr].y * scale);
        fn[(size_t)(row0 + rr) * (DD / 2) + lane] =
            (unsigned int)a | ((unsigned int)bb << 16);
    }
}

// ABLATION PROBE on the R8 champion structure.
// MODE 0 = full (production, correct output)
// MODE 1 = no stores (asm keep-alive on av/sv)
// MODE 2 = no epilogue math (av=cv, sv=cv; stores kept)
// MODE 3 = no fragment loads / no MFMA (acc = opaque zero; epilogue+stores kept)
// REPS inner repetitions (opaque pointers per rep prevent CSE) so each
// dispatch outranks the harness's 80us fill kernels in the rocprof table.
template <int MODE, int REPS>
__global__ __launch_bounds__(256, 4) void ASG_adj_probe(
    const unsigned short* __restrict__ fn, const float* __restrict__ coord,
    float* __restrict__ out)
{
    const int id  = blockIdx.x;        // 0..2047
    const int xcd = id & 7;
    const int q   = id >> 3;           // 0..255
    const int b   = xcd + 8 * (q >> 5);
    const int t   = q & 31;
    const int bi  = t >> 3;            // 128-row stripe 0..3
    const int bj  = t & 7;             // 64-col stripe 0..7

    const int tid = threadIdx.x;
    const int wid = tid >> 6, lane = tid & 63;
    const int wr  = wid >> 1, wc = wid & 1;
    const int row0 = bi * 128 + wr * 64;
    const int col0 = bj * 64  + wc * 32;
    const int lo = lane & 15, hi = lane >> 4;

    __shared__ float2 crow[128];
    __shared__ float2 ccol[64];
    __shared__ float  xpose[4][16 * 36];   // per-wave transpose buf (pad 36)

    const float2* cb = reinterpret_cast<const float2*>(coord) + (size_t)b * NN;
    if (tid < 128)      crow[tid] = cb[bi * 128 + tid];
    else if (tid < 192) ccol[tid - 128] = cb[bj * 64 + (tid - 128)];
    __syncthreads();

    const unsigned short* fb_base = fn + (size_t)b * NN * DD;
    float* oA_base = out + (size_t)b * NN * NN;
    float* oS_base = out + (size_t)NB * NN * NN + (size_t)b * NN * NN;
    const int lk = hi * 8;             // k start (bf16 elements)

    float* xp = xpose[wid];
    const int c4 = (lane & 7) * 4;
    const int jbase = col0 + c4;
    float2 cj[4];
#pragma unroll
    for (int q2 = 0; q2 < 4; ++q2) cj[q2] = ccol[wc * 32 + c4 + q2];

#pragma unroll 1
    for (int rep = 0; rep < REPS; ++rep) {
        // opaque roots: force re-execution of loads/compute each rep
        const unsigned short* fb = fb_base;
        float* outA = oA_base;
        float* outS = oS_base;
        asm volatile("" : "+v"(fb), "+v"(outA), "+v"(outS));
        float zopq = 0.0f;
        if constexpr (MODE == 3) asm volatile("" : "+v"(zopq));

        bf16x8 bfrag[2][4];
        if constexpr (MODE != 3) {
#pragma unroll
            for (int n = 0; n < 2; ++n) {
                const unsigned short* p =
                    fb + (size_t)(col0 + n * 16 + lo) * DD + lk;
#pragma unroll
                for (int kk = 0; kk < 4; ++kk)
                    bfrag[n][kk] = *reinterpret_cast<const bf16x8*>(p + kk * 32);
            }
        }

#define LOADA(DST, MM)                                                        \
        if constexpr (MODE != 3) {                                            \
            const unsigned short* p =                                         \
                fb + (size_t)(row0 + (MM) * 16 + lo) * DD + lk;               \
            _Pragma("unroll")                                                 \
            for (int kk = 0; kk < 4; ++kk)                                    \
                DST[kk] = *reinterpret_cast<const bf16x8*>(p + kk * 32);      \
        }

#define STEP(MM, CURF, NEXTF, DO_PREF)                                       \
        {                                                                     \
            if (DO_PREF) LOADA(NEXTF, (MM) + 1);                              \
            f32x4 acc[2];                                                     \
            if constexpr (MODE != 3) {                                        \
                _Pragma("unroll")                                             \
                for (int n = 0; n < 2; ++n)                                   \
                    acc[n] = (f32x4){0.f, 0.f, 0.f, 0.f};                     \
                _Pragma("unroll")                                             \
                for (int n = 0; n < 2; ++n)                                   \
                    _Pragma("unroll")                                         \
                    for (int kk = 0; kk < 4; ++kk)                            \
                        acc[n] = __builtin_amdgcn_mfma_f32_16x16x32_bf16(     \
                            CURF[kk], bfrag[n][kk], acc[n], 0, 0, 0);         \
            } else {                                                          \
                _Pragma("unroll")                                             \
                for (int n = 0; n < 2; ++n)                                   \
                    acc[n] = (f32x4){zopq, zopq, zopq, zopq};                 \
            }                                                                 \
            _Pragma("unroll")                                                 \
            for (int n = 0; n < 2; ++n)                                       \
                _Pragma("unroll")                                             \
                for (int r = 0; r < 4; ++r)                                   \
                    xp[(hi * 4 + r) * 36 + n * 16 + lo] = acc[n][r];          \
            _Pragma("unroll")                                                 \
            for (int p2 = 0; p2 < 2; ++p2) {                                  \
                const int rr = p2 * 8 + (lane >> 3);                          \
                const f32x4 cv =                                              \
                    *reinterpret_cast<const f32x4*>(&xp[rr * 36 + c4]);       \
                const int i = row0 + (MM) * 16 + rr;                          \
                const float2 ci = crow[wr * 64 + (MM) * 16 + rr];             \
                f32x4 av, sv;                                                 \
                if constexpr (MODE == 2) {                                    \
                    av = cv; sv = cv; (void)ci;                               \
                } else {                                                      \
                    _Pragma("unroll")                                         \
                    for (int q2 = 0; q2 < 4; ++q2) {                          \
                        const int j = jbase + q2;                             \
                        const float dx = ci.x - cj[q2].x;                     \
                        const float dy = ci.y - cj[q2].y;                     \
                        const float d2 =                                      \
                            __fadd_rn(__fmul_rn(dx, dx), __fmul_rn(dy, dy));  \
                        const float dist = __fsqrt_rn(d2);                    \
                        const bool diag = (i == j);                           \
                        av[q2] = diag ? 0.0f : cv[q2] * __expf(-dist);        \
                        sv[q2] = (!diag && dist < 1.0f) ? 1.0f : 0.0f;        \
                    }                                                         \
                }                                                             \
                if constexpr (MODE == 1) {                                    \
                    asm volatile("" :: "v"(av[0]), "v"(av[1]), "v"(av[2]),    \
                                       "v"(av[3]), "v"(sv[0]), "v"(sv[1]),    \
                                       "v"(sv[2]), "v"(sv[3]));               \
                } else {                                                      \
                    const size_t off = (size_t)i * NN + jbase;                \
                    *reinterpret_cast<f32x4*>(outA + off) = av;               \
                    *reinterpret_cast<f32x4*>(outS + off) = sv;               \
                }                                                             \
            }                                                                 \
        }

        bf16x8 af0[4], af1[4];
        LOADA(af0, 0);
        STEP(0, af0, af1, 1);
        STEP(1, af1, af0, 1);
        STEP(2, af0, af1, 1);
        STEP(3, af1, af0, 0);

#undef STEP
#undef LOADA
    }
}

extern "C" void kernel_launch(void* const* d_in, const int* in_sizes, int n_in,
                              void* d_out, int out_size, void* d_ws, size_t ws_size,
                              hipStream_t stream) {
    const float* fea   = (const float*)d_in[0];   // [64,512,128] f32
    const float* coord = (const float*)d_in[1];   // [64,512,2]   f32
    float* out = (float*)d_out;                   // [2,64,512,512] f32
    unsigned int* fn_ws = (unsigned int*)d_ws;    // bf16 fn, 8 MB
    const unsigned short* fn = (const unsigned short*)fn_ws;

    ASG_norm_kernel<<<dim3(2048), 256, 0, stream>>>(fea, fn_ws);
    // probes (x6 reps each so they outrank the 80us fills in rocprof)
    ASG_adj_probe<1, 6><<<dim3(2048), 256, 0, stream>>>(fn, coord, out); // nostore
    ASG_adj_probe<3, 6><<<dim3(2048), 256, 0, stream>>>(fn, coord, out); // nomfma
    ASG_adj_probe<2, 6><<<dim3(2048), 256, 0, stream>>>(fn, coord, out); // noepi
    // production pass LAST -> correct final output
    ASG_adj_probe<0, 6><<<dim3(2048), 256, 0, stream>>>(fn, coord, out); // full
}

// Round 14
// 52.567 us; speedup vs baseline: 10.4286x; 10.4286x over previous
//
#include <hip/hip_runtime.h>
#include <hip/hip_bf16.h>

typedef short bf16x8 __attribute__((ext_vector_type(8)));
typedef float f32x4  __attribute__((ext_vector_type(4)));

#define NB 64
#define NN 512
#define DD 128

// RNE float -> bf16 (finite inputs)
__device__ __forceinline__ unsigned short f2bf(float f) {
    unsigned int u = __float_as_uint(f);
    unsigned int r = (u + 0x7FFFu + ((u >> 16) & 1u)) >> 16;
    return (unsigned short)r;
}

// Kernel 1: per-row L2 normalize, write bf16 fn into workspace (XCD-pinned).
__global__ __launch_bounds__(256) void ASG_norm_kernel(
    const float* __restrict__ fea, unsigned int* __restrict__ fn)
{
    const int id   = blockIdx.x;        // 0..2047
    const int xcd  = id & 7;
    const int q    = id >> 3;           // 0..255
    const int b    = xcd + 8 * (q >> 5);
    const int t    = q & 31;            // 32 blocks/batch, 16 rows each
    const int wid  = threadIdx.x >> 6;
    const int lane = threadIdx.x & 63;
    const int row0 = b * NN + t * 16 + wid * 4;
    const float2* src = reinterpret_cast<const float2*>(fea);

    float2 v[4];
    float  s[4];
#pragma unroll
    for (int rr = 0; rr < 4; ++rr) {
        v[rr] = src[(size_t)(row0 + rr) * (DD / 2) + lane];
        s[rr] = v[rr].x * v[rr].x + v[rr].y * v[rr].y;
    }
#pragma unroll
    for (int o = 32; o; o >>= 1) {
#pragma unroll
        for (int rr = 0; rr < 4; ++rr) s[rr] += __shfl_xor(s[rr], o);
    }
#pragma unroll
    for (int rr = 0; rr < 4; ++rr) {
        const float scale = 1.0f / fmaxf(sqrtf(s[rr]), 1e-8f);
        const unsigned short a = f2bf(v[rr].x * scale);
        const unsigned short bb = f2bf(v[rr].y * scale);
        fn[(size_t)(row0 + rr) * (DD / 2) + lane] =
            (unsigned int)a | ((unsigned int)bb << 16);
    }
}

// Kernel 2: block = 16 rows x FULL 512 cols (one row band per block).
// Wave = 16x128 col band. n-loop MFMA (2-deep B prefetch) -> wave-private
// LDS transpose -> A-phase: 8 stores of 2 rows x 512B contiguous (4 waves
// jointly complete full 2KB rows), then S-phase separately (planes never
// interleave). Store stream per XCD is near-linear, mimicking the 6.9 TB/s
// fill kernel. Probe (R13) showed compute hides fully under stores.
__global__ __launch_bounds__(256, 4) void ASG_adj_kernel(
    const unsigned short* __restrict__ fn, const float* __restrict__ coord,
    float* __restrict__ out)
{
    const int id  = blockIdx.x;        // 0..2047
    const int xcd = id & 7;
    const int qq  = id >> 3;           // 0..255
    const int b   = xcd + 8 * (qq >> 5);
    const int t   = qq & 31;           // row band
    const int i0  = t * 16;

    const int tid = threadIdx.x;
    const int wid = tid >> 6, lane = tid & 63;
    const int c0  = wid * 128;         // wave's col band
    const int lo = lane & 15, hi = lane >> 4;

    __shared__ float2 ccol[NN];
    __shared__ float2 crow[16];
    __shared__ float  xpose[4][16 * 132];  // wave-private, stride 132

    const float2* cb = reinterpret_cast<const float2*>(coord) + (size_t)b * NN;
    ccol[tid]       = cb[tid];
    ccol[tid + 256] = cb[tid + 256];
    if (tid < 16) crow[tid] = cb[i0 + tid];
    __syncthreads();

    const unsigned short* fb = fn + (size_t)b * NN * DD;
    const int lk = hi * 8;             // k start (bf16 elements)

    // A fragments: block's 16 rows (shared by all n), 4 dwordx4
    bf16x8 afrag[4];
    {
        const unsigned short* p = fb + (size_t)(i0 + lo) * DD + lk;
#pragma unroll
        for (int kk = 0; kk < 4; ++kk)
            afrag[kk] = *reinterpret_cast<const bf16x8*>(p + kk * 32);
    }

    float* xp = xpose[wid];

#define LOADB(DST, N)                                                         \
    {                                                                         \
        const unsigned short* p =                                             \
            fb + (size_t)(c0 + (N) * 16 + lo) * DD + lk;                      \
        _Pragma("unroll")                                                     \
        for (int kk = 0; kk < 4; ++kk)                                        \
            DST[kk] = *reinterpret_cast<const bf16x8*>(p + kk * 32);          \
    }

#define STEPN(N, CUR, NXT, PREF)                                              \
    {                                                                         \
        if (PREF) LOADB(NXT, (N) + 1);                                        \
        f32x4 acc = (f32x4){0.f, 0.f, 0.f, 0.f};                              \
        _Pragma("unroll")                                                     \
        for (int kk = 0; kk < 4; ++kk)                                        \
            acc = __builtin_amdgcn_mfma_f32_16x16x32_bf16(                    \
                afrag[kk], CUR[kk], acc, 0, 0, 0);                            \
        _Pragma("unroll")                                                     \
        for (int r = 0; r < 4; ++r)                                           \
            xp[(hi * 4 + r) * 132 + (N) * 16 + lo] = acc[r];                  \
    }

    bf16x8 bf0[4], bf1[4];
    LOADB(bf0, 0);
    STEPN(0, bf0, bf1, 1);
    STEPN(1, bf1, bf0, 1);
    STEPN(2, bf0, bf1, 1);
    STEPN(3, bf1, bf0, 1);
    STEPN(4, bf0, bf1, 1);
    STEPN(5, bf1, bf0, 1);
    STEPN(6, bf0, bf1, 1);
    STEPN(7, bf1, bf0, 0);
#undef STEPN
#undef LOADB

    // Epilogue: per instr, 2 rows x 128 cols (512B/row run per wave;
    // 4 waves jointly cover the full 2KB row).
    const int rsel = lane >> 5;            // 0/1
    const int csel = (lane & 31) * 4;      // col within wave band
    const int jb = c0 + csel;
    float2 cj[4];
#pragma unroll
    for (int c = 0; c < 4; ++c) cj[c] = ccol[jb + c];

    float* outA = out + (size_t)b * NN * NN;
    float* outS = out + (size_t)NB * NN * NN + (size_t)b * NN * NN;

    // A-phase: ascending, single plane
#pragma unroll
    for (int p = 0; p < 8; ++p) {
        const int lr = p * 2 + rsel;       // local row 0..15
        const f32x4 cv = *reinterpret_cast<const f32x4*>(&xp[lr * 132 + csel]);
        const int i = i0 + lr;
        const float2 ci = crow[lr];
        f32x4 av;
#pragma unroll
        for (int c = 0; c < 4; ++c) {
            // bit-exact numpy chain: mul, mul, add, sqrt (no FMA)
            const float dx = ci.x - cj[c].x;
            const float dy = ci.y - cj[c].y;
            const float d2 = __fadd_rn(__fmul_rn(dx, dx), __fmul_rn(dy, dy));
            const float dist = __fsqrt_rn(d2);
            const bool diag = (i == jb + c);
            av[c] = diag ? 0.0f : cv[c] * __expf(-dist);
        }
        *reinterpret_cast<f32x4*>(outA + (size_t)i * NN + jb) = av;
    }

    // S-phase: ascending, single plane (dist recomputed — VALU is free)
#pragma unroll
    for (int p = 0; p < 8; ++p) {
        const int lr = p * 2 + rsel;
        const int i = i0 + lr;
        const float2 ci = crow[lr];
        f32x4 sv;
#pragma unroll
        for (int c = 0; c < 4; ++c) {
            const float dx = ci.x - cj[c].x;
            const float dy = ci.y - cj[c].y;
            const float d2 = __fadd_rn(__fmul_rn(dx, dx), __fmul_rn(dy, dy));
            const float dist = __fsqrt_rn(d2);
            const bool diag = (i == jb + c);
            sv[c] = (!diag && dist < 1.0f) ? 1.0f : 0.0f;
        }
        *reinterpret_cast<f32x4*>(outS + (size_t)i * NN + jb) = sv;
    }
}

extern "C" void kernel_launch(void* const* d_in, const int* in_sizes, int n_in,
                              void* d_out, int out_size, void* d_ws, size_t ws_size,
                              hipStream_t stream) {
    const float* fea   = (const float*)d_in[0];   // [64,512,128] f32
    const float* coord = (const float*)d_in[1];   // [64,512,2]   f32
    float* out = (float*)d_out;                   // [2,64,512,512] f32
    unsigned int* fn_ws = (unsigned int*)d_ws;    // bf16 fn, 8 MB

    ASG_norm_kernel<<<dim3(2048), 256, 0, stream>>>(fea, fn_ws);
    ASG_adj_kernel<<<dim3(2048), 256, 0, stream>>>(
        (const unsigned short*)fn_ws, coord, out);
}